// Round 1
// 1247.989 us; speedup vs baseline: 1.3134x; 1.3134x over previous
//
#include <hip/hip_runtime.h>
#include <math.h>

#define NBATCH 512
#define TSTEPS 10
#define NIMG   5120   // NBATCH*TSTEPS
#define FEAT   616
#define NEDGE  8192

__device__ __forceinline__ float sigf(float x){ return 1.f/(1.f + expf(-x)); }

// ---------------- prep: weight transposes + zero BN stats ----------------
__global__ void prep_kernel(const float* __restrict__ s1wl, const float* __restrict__ s1wr,
                            const float* __restrict__ s2wl, const float* __restrict__ s2wr,
                            const float* __restrict__ wih,  const float* __restrict__ whh,
                            float* __restrict__ wlT, float* __restrict__ wrT,
                            float* __restrict__ wl2T, float* __restrict__ wr2T,
                            float* __restrict__ wihT, float* __restrict__ whhT,
                            double* __restrict__ stats)
{
  int idx = blockIdx.x*256 + threadIdx.x;
  if (idx < 39424){ wlT[(idx%616)*64 + idx/616] = s1wl[idx]; return; }
  idx -= 39424;
  if (idx < 39424){ wrT[(idx%616)*64 + idx/616] = s1wr[idx]; return; }
  idx -= 39424;
  if (idx < 2048){ wl2T[(idx%64)*32 + idx/64] = s2wl[idx]; return; }
  idx -= 2048;
  if (idx < 2048){ wr2T[(idx%64)*32 + idx/64] = s2wr[idx]; return; }
  idx -= 2048;
  if (idx < 8192){ wihT[(idx%32)*256 + idx/32] = wih[idx]; return; }
  idx -= 8192;
  if (idx < 16384){ whhT[(idx%64)*256 + idx/64] = whh[idx]; return; }
  idx -= 16384;
  if (idx < 1280){ stats[idx] = 0.0; }
}

// ---------------- CSR build for scatter-max (dst-grouped) ----------------
__global__ void csr_kernel(const int* __restrict__ edges, int* __restrict__ row_start,
                           int* __restrict__ adj)
{
  __shared__ int cnt_s[512];
  __shared__ int scan_s[512];
  const int tid = threadIdx.x;
  const int* src = edges;
  const int* dst = edges + NEDGE;
  cnt_s[tid] = 0;
  __syncthreads();
  for (int e = tid; e < NEDGE; e += 512) atomicAdd(&cnt_s[dst[e]], 1);
  __syncthreads();
  int v = cnt_s[tid];
  scan_s[tid] = v;
  __syncthreads();
  for (int off = 1; off < 512; off <<= 1){
    int add = (tid >= off) ? scan_s[tid - off] : 0;
    __syncthreads();
    scan_s[tid] += add;
    __syncthreads();
  }
  int start = scan_s[tid] - v;
  row_start[tid] = start;
  if (tid == 511) row_start[512] = scan_s[511];
  cnt_s[tid] = start;   // reuse as cursor
  __syncthreads();
  for (int e = tid; e < NEDGE; e += 512){
    int d = dst[e];
    int pos = atomicAdd(&cnt_s[d], 1);
    adj[pos] = src[e];
  }
}

// ---------------- conv1 (3x3 SAME, CIN->16), SINGLE PASS ----------------
// Computes conv once; accumulates BN stats (pre-BN sum/sumsq) AND writes the
// pre-BN per-2x2-window extremum to `pooled` in the same pass.
// Key identity: BN is per-(t,ch) affine y = sc*z + sh with sign(sc)=sign(g)
// (sc = g*rsqrt(var+eps), rsqrt>0), and relu/affine are monotone, so
//   maxpool(relu(sc*z+sh)) = relu(sc * extremum(z) + sh),
// extremum = max if g>=0 else min. g is known BEFORE stats, so one pass
// suffices; conv2 applies the affine+relu at stage-in time (bit-exact:
// fma/relu rounding is monotone, picks the same window element).
template<int CIN>
__launch_bounds__(320)
__global__ void conv1_kernel(const float* __restrict__ in, const float* __restrict__ w,
                             const float* __restrict__ g,
                             double* __restrict__ stats, float* __restrict__ pooled)
{
  __shared__ __attribute__((aligned(16))) float in_t[CIN*792];   // [ci][18][44] halo
  __shared__ __attribute__((aligned(16))) float wl[CIN*144];     // [ci][tap][16]
  __shared__ __attribute__((aligned(16))) float red[2560];       // stats scratch
  __shared__ float gsh[16];
  const int tid = threadIdx.x;
  const int bid = blockIdx.x;
  const int img = bid / 3, strip = bid % 3;
  const int y0 = strip * 16;
  const int t = img % TSTEPS;
  const float* imgp = in + (size_t)img * CIN * 1600;

  if (tid < 16) gsh[tid] = g[tid];
  for (int idx = tid; idx < CIN*144; idx += 320){
    int co = idx & 15, rest = idx >> 4;
    int k = rest % 9, ci = rest / 9;
    wl[(ci*9 + k)*16 + co] = w[(co*CIN + ci)*9 + k];
  }
  for (int idx = tid; idx < CIN*792; idx += 320){
    int ci = idx / 792, rem = idx % 792;
    int r = rem / 44, cc = rem % 44;
    int gy = y0 + r - 1, gx = cc - 1;
    float v = 0.f;
    if (cc < 42 && gy >= 0 && gy < 40 && gx >= 0 && gx < 40) v = imgp[ci*1600 + gy*40 + gx];
    in_t[idx] = v;
  }
  __syncthreads();

  const int pos = tid % 80, cog = tid / 80;
  const int row = pos & 15, oct = pos >> 4;   // 16 rows x 5 octets
  const int x8 = oct * 8;
  const int co0 = cog * 4;
  const int gy = y0 + row;
  const bool act = gy < 40;

  float acc[8][4];                             // [px][co]
  #pragma unroll
  for (int i = 0; i < 8; i++)
    #pragma unroll
    for (int j = 0; j < 4; j++) acc[i][j] = 0.f;

  for (int ci = 0; ci < CIN; ci++){
    float v[3][10];
    #pragma unroll
    for (int r = 0; r < 3; r++){
      const float* rp = &in_t[ci*792 + (row + r)*44 + x8];
      const float4 a = *(const float4*)rp;
      const float4 b = *(const float4*)(rp + 4);
      const float2 c = *(const float2*)(rp + 8);
      v[r][0] = a.x; v[r][1] = a.y; v[r][2] = a.z; v[r][3] = a.w;
      v[r][4] = b.x; v[r][5] = b.y; v[r][6] = b.z; v[r][7] = b.w;
      v[r][8] = c.x; v[r][9] = c.y;
    }
    #pragma unroll
    for (int dy = 0; dy < 3; dy++)
      #pragma unroll
      for (int dx = 0; dx < 3; dx++){
        const float4 wv = *(const float4*)&wl[(ci*9 + dy*3 + dx)*16 + co0];
        #pragma unroll
        for (int px = 0; px < 8; px++){
          float iv = v[dy][px + dx];
          acc[px][0] += iv*wv.x; acc[px][1] += iv*wv.y;
          acc[px][2] += iv*wv.z; acc[px][3] += iv*wv.w;
        }
      }
  }

  // ---- stats partials (pre-BN sum / sumsq) ----
  #pragma unroll
  for (int cl = 0; cl < 4; cl++){
    float s = 0.f, q = 0.f;
    #pragma unroll
    for (int px = 0; px < 8; px++){
      float a = acc[px][cl];
      s += a; q += a*a;
    }
    red[(co0 + cl)*80 + pos]        = act ? s : 0.f;
    red[1280 + (co0 + cl)*80 + pos] = act ? q : 0.f;
  }

  // ---- pre-BN signed extremum 2x2 pool (in registers + shfl) ----
  const int py = strip*8 + (row >> 1);
  #pragma unroll
  for (int cl = 0; cl < 4; cl++){
    const bool mx = gsh[co0 + cl] >= 0.f;
    float hp[4];
    #pragma unroll
    for (int j = 0; j < 4; j++){
      float a = acc[2*j][cl], b = acc[2*j + 1][cl];
      hp[j] = mx ? fmaxf(a, b) : fminf(a, b);
    }
    float op[4];
    #pragma unroll
    for (int j = 0; j < 4; j++) op[j] = __shfl_xor(hp[j], 1, 64);
    if (act && !(row & 1)){
      float4 r4;
      if (mx){
        r4.x = fmaxf(hp[0], op[0]); r4.y = fmaxf(hp[1], op[1]);
        r4.z = fmaxf(hp[2], op[2]); r4.w = fmaxf(hp[3], op[3]);
      } else {
        r4.x = fminf(hp[0], op[0]); r4.y = fminf(hp[1], op[1]);
        r4.z = fminf(hp[2], op[2]); r4.w = fminf(hp[3], op[3]);
      }
      *(float4*)&pooled[(size_t)img*6400 + (co0 + cl)*400 + py*20 + oct*4] = r4;
    }
  }
  __syncthreads();

  // ---- stats reduction ----
  if (tid < 256){
    int co = tid >> 4, seg = tid & 15;
    float vs = 0.f, vq = 0.f;
    #pragma unroll
    for (int j = 0; j < 5; j++){
      vs += red[co*80 + seg*5 + j];
      vq += red[1280 + co*80 + seg*5 + j];
    }
    #pragma unroll
    for (int off = 8; off > 0; off >>= 1){
      vs += __shfl_down(vs, off, 16);
      vq += __shfl_down(vq, off, 16);
    }
    if (seg == 0){
      atomicAdd(&stats[(t*16 + co)*2 + 0], (double)vs);
      atomicAdd(&stats[(t*16 + co)*2 + 1], (double)vq);
    }
  }
}

// ---------------- conv2 (3x3 SAME, 16->CO on 20x20), SINGLE PASS ----------------
// Stage-in applies BN1 affine+relu to the pre-BN pooled extremum. Computes
// conv once, accumulates conv2 stats, writes raw z2 IN-PLACE over this
// image's pooled region (all pooled reads for the image complete before the
// first sync, so per-image aliasing is race-free).
template<int CO>
__launch_bounds__(256)
__global__ void conv2_kernel(float* __restrict__ pooled, const float* __restrict__ w,
                             const float* __restrict__ bnp1, double* __restrict__ stats)
{
  constexpr int R = (CO == 16) ? 2 : 1;
  constexpr int P = (20/R) * 5;                 // pixel positions: 50 or 100
  __shared__ __attribute__((aligned(16))) float in_t[16*528];   // [16][22][24] halo
  __shared__ __attribute__((aligned(16))) float wl[144*CO];     // [ci][k][CO]
  __shared__ float sc1s[16], sh1s[16];
  const int tid = threadIdx.x;
  const int img = blockIdx.x;
  const int t = img % TSTEPS;
  float* ip = pooled + (size_t)img * 6400;

  if (tid < 16){
    sc1s[tid] = bnp1[(t*16 + tid)*2 + 0];
    sh1s[tid] = bnp1[(t*16 + tid)*2 + 1];
  }
  __syncthreads();

  for (int idx = tid; idx < 144*CO; idx += 256){
    int co = idx % CO, rest = idx / CO;
    int k = rest % 9, ci = rest / 9;
    wl[(ci*9 + k)*CO + co] = w[(co*16 + ci)*9 + k];
  }
  for (int idx = tid; idx < 16*528; idx += 256){
    int ci = idx / 528, rem = idx % 528;
    int r = rem / 24, cc = rem % 24;
    int gy = r - 1, gx = cc - 1;
    float v = 0.f;
    if (cc < 22 && gy >= 0 && gy < 20 && gx >= 0 && gx < 20)
      v = fmaxf(fmaf(ip[ci*400 + gy*20 + gx], sc1s[ci], sh1s[ci]), 0.f);
    in_t[idx] = v;
  }
  __syncthreads();

  const bool act = tid < P*(CO/4);
  const int q = tid % P, cog = tid / P;
  const int x4 = (q % 5) * 4, yb = (q / 5) * R;
  const int co0 = cog * 4;
  float acc[R][4][4];                           // [row][px][co]
  #pragma unroll
  for (int rr = 0; rr < R; rr++)
    #pragma unroll
    for (int i = 0; i < 4; i++)
      #pragma unroll
      for (int j = 0; j < 4; j++) acc[rr][i][j] = 0.f;

  if (act){
    for (int ci = 0; ci < 16; ci++){
      float v[R + 2][6];
      #pragma unroll
      for (int r = 0; r < R + 2; r++){
        const float* rp = &in_t[ci*528 + (yb + r)*24 + x4];
        const float4 a = *(const float4*)rp;
        const float2 b = *(const float2*)(rp + 4);
        v[r][0] = a.x; v[r][1] = a.y; v[r][2] = a.z; v[r][3] = a.w;
        v[r][4] = b.x; v[r][5] = b.y;
      }
      #pragma unroll
      for (int dy = 0; dy < 3; dy++)
        #pragma unroll
        for (int dx = 0; dx < 3; dx++){
          const float4 wv = *(const float4*)&wl[(ci*9 + dy*3 + dx)*CO + co0];
          #pragma unroll
          for (int rr = 0; rr < R; rr++){
            #pragma unroll
            for (int px = 0; px < 4; px++){
              float iv = v[rr + dy][px + dx];
              acc[rr][px][0] += iv*wv.x; acc[rr][px][1] += iv*wv.y;
              acc[rr][px][2] += iv*wv.z; acc[rr][px][3] += iv*wv.w;
            }
          }
        }
    }
  }
  __syncthreads();   // everyone done reading in_t (and ip); reuse both below

  if (act){
    #pragma unroll
    for (int cl = 0; cl < 4; cl++){
      // stats partials
      float s = 0.f, qq = 0.f;
      #pragma unroll
      for (int rr = 0; rr < R; rr++)
        #pragma unroll
        for (int px = 0; px < 4; px++){
          float a = acc[rr][px][cl];
          s += a; qq += a*a;
        }
      in_t[(co0 + cl)*P + q]            = s;
      in_t[CO*P + (co0 + cl)*P + q]     = qq;
      // raw z2 write, in place over this image's pooled region
      #pragma unroll
      for (int rr = 0; rr < R; rr++){
        float4 z4;
        z4.x = acc[rr][0][cl]; z4.y = acc[rr][1][cl];
        z4.z = acc[rr][2][cl]; z4.w = acc[rr][3][cl];
        *(float4*)&ip[(co0 + cl)*400 + (yb + rr)*20 + x4] = z4;
      }
    }
  }
  __syncthreads();
  if (tid < CO*8){
    int co = tid >> 3, seg = tid & 7;
    float vs = 0.f, vq = 0.f;
    for (int j = seg; j < P; j += 8){
      vs += in_t[co*P + j];
      vq += in_t[CO*P + co*P + j];
    }
    #pragma unroll
    for (int off = 4; off > 0; off >>= 1){
      vs += __shfl_down(vs, off, 8);
      vq += __shfl_down(vq, off, 8);
    }
    if (seg == 0){
      atomicAdd(&stats[(t*CO + co)*2 + 0], (double)vs);
      atomicAdd(&stats[(t*CO + co)*2 + 1], (double)vq);
    }
  }
}

// ---------------- conv2 epilogue: BN2 + relu + 4x4 avgpool -> feats ----------------
// Reads raw z2 (just written, LLC-resident). One thread per output element.
template<int CO>
__global__ void conv2_epi_kernel(const float* __restrict__ pooled, const float* __restrict__ bnp,
                                 float* __restrict__ feats, int featBase)
{
  int idx = blockIdx.x*256 + threadIdx.x;
  if (idx >= NIMG*CO*25) return;
  const int q = idx % 25;
  const int rest = idx / 25;
  const int co = rest % CO, img = rest / CO;
  const int t = img % TSTEPS, n = img / TSTEPS;
  const int py = q / 5, px = q % 5;
  const float* zp = pooled + (size_t)img*6400 + co*400;
  const float sc = bnp[(t*CO + co)*2 + 0];
  const float sh = bnp[(t*CO + co)*2 + 1];
  float s = 0.f;
  #pragma unroll
  for (int r = 0; r < 4; r++){
    const float4 v = *(const float4*)&zp[(py*4 + r)*20 + px*4];
    s += fmaxf(fmaf(v.x, sc, sh), 0.f);
    s += fmaxf(fmaf(v.y, sc, sh), 0.f);
    s += fmaxf(fmaf(v.z, sc, sh), 0.f);
    s += fmaxf(fmaf(v.w, sc, sh), 0.f);
  }
  feats[(size_t)(t*NBATCH + n)*FEAT + featBase + co*25 + q] = s * 0.0625f;
}

// ---------------- BN params from stats ----------------
__global__ void bn_param_kernel(const double* __restrict__ stats, float* __restrict__ bnp,
                                const float* __restrict__ g, const float* __restrict__ be,
                                int C, double invCnt)
{
  int idx = threadIdx.x;
  if (idx < TSTEPS*C){
    int c = idx % C;
    double mean = stats[idx*2] * invCnt;
    double var  = stats[idx*2 + 1] * invCnt - mean*mean;
    if (var < 0.0) var = 0.0;
    double sc = (double)g[c] / sqrt(var + 1e-5);
    bnp[idx*2]     = (float)sc;
    bnp[idx*2 + 1] = be[c] - (float)(mean * sc);
  }
}

// ---------------- embedding fill ----------------
__global__ void emb_kernel(const int* __restrict__ irr, const float* __restrict__ emb,
                           float* __restrict__ feats)
{
  int idx = blockIdx.x*256 + threadIdx.x;
  if (idx >= NBATCH*TSTEPS*16) return;
  int k = idx & 15;
  int nt = idx >> 4;              // n*10 + t
  int t = nt % TSTEPS, n = nt / TSTEPS;
  feats[(size_t)(t*NBATCH + n)*FEAT + 600 + k] = emb[irr[nt]*16 + k];
}

// ---------------- SAGE scatter-max (CSR gather) ----------------
__global__ void agg_kernel(const float* __restrict__ feats, const int* __restrict__ row_start,
                           const int* __restrict__ adj, float* __restrict__ agg)
{
  __shared__ int adjs[192];
  const int bid = blockIdx.x;
  const int t = bid / NBATCH, n = bid % NBATCH;
  const int tid = threadIdx.x;
  const int rs = row_start[n], re = row_start[n + 1];
  const int deg = re - rs;
  for (int i = tid; i < deg && i < 192; i += 256) adjs[i] = adj[rs + i];
  __syncthreads();
  const float* fb = feats + (size_t)t*NBATCH*FEAT;
  float* ab = agg + (size_t)(t*NBATCH + n)*FEAT;
  for (int f = tid; f < FEAT; f += 256){
    float m = -1e30f;
    for (int j = 0; j < deg; j++){
      int s = (j < 192) ? adjs[j] : adj[rs + j];
      m = fmaxf(m, fb[(size_t)s*FEAT + f]);
    }
    ab[f] = (deg > 0) ? m : 0.f;
  }
}

// ---------------- SAGE1: out = relu(agg@wl^T + bl + x@wr^T), 616->64 ----------------
__launch_bounds__(256)
__global__ void sage1_kernel(const float* __restrict__ feats, const float* __restrict__ agg,
                             const float* __restrict__ wlT, const float* __restrict__ wrT,
                             const float* __restrict__ bl, float* __restrict__ x1)
{
  __shared__ float xr[4][616];
  __shared__ float ar[4][616];
  const int tid = threadIdx.x;
  const int bid = blockIdx.x;
  for (int idx = tid; idx < 4*616; idx += 256){
    int r = idx / 616, f = idx % 616;
    size_t row = (size_t)bid*4 + r;
    xr[r][f] = feats[row*FEAT + f];
    ar[r][f] = agg[row*FEAT + f];
  }
  __syncthreads();
  const int wid = tid >> 6, o = tid & 63;
  const int row = bid*4 + wid;
  float acc = bl[o];
  #pragma unroll 4
  for (int f = 0; f < 616; f++){
    acc += ar[wid][f]*wlT[f*64 + o] + xr[wid][f]*wrT[f*64 + o];
  }
  x1[(size_t)row*64 + o] = fmaxf(acc, 0.f);
}

// ---------------- SAGE2: 64->32 with its own scatter-max ----------------
__launch_bounds__(64)
__global__ void sage2_kernel(const float* __restrict__ x1, const int* __restrict__ row_start,
                             const int* __restrict__ adj, const float* __restrict__ wl2T,
                             const float* __restrict__ wr2T, const float* __restrict__ bl2,
                             float* __restrict__ x2)
{
  __shared__ float am[64], xm[64];
  __shared__ int adjs[192];
  const int bid = blockIdx.x;
  const int t = bid / NBATCH, n = bid % NBATCH;
  const int lane = threadIdx.x;
  const int rs = row_start[n], re = row_start[n + 1];
  const int deg = re - rs;
  for (int i = lane; i < deg && i < 192; i += 64) adjs[i] = adj[rs + i];
  __syncthreads();
  const float* xb = x1 + (size_t)t*NBATCH*64;
  float m = -1e30f;
  for (int j = 0; j < deg; j++){
    int s = (j < 192) ? adjs[j] : adj[rs + j];
    m = fmaxf(m, xb[s*64 + lane]);
  }
  am[lane] = (deg > 0) ? m : 0.f;
  xm[lane] = xb[n*64 + lane];
  __syncthreads();
  if (lane < 32){
    float acc = bl2[lane];
    #pragma unroll 4
    for (int f = 0; f < 64; f++){
      acc += am[f]*wl2T[f*32 + lane] + xm[f]*wr2T[f*32 + lane];
    }
    x2[(size_t)(t*NBATCH + n)*32 + lane] = fmaxf(acc, 0.f);
  }
}

// ---------------- fused LSTM (per-sample) + final FC ----------------
__launch_bounds__(256)
__global__ void lstm_kernel(const float* __restrict__ x2, const float* __restrict__ wihT,
                            const float* __restrict__ whhT, const float* __restrict__ bih,
                            const float* __restrict__ bhh, const float* __restrict__ fcw,
                            const float* __restrict__ fcb, float* __restrict__ out)
{
  __shared__ float xb[32], hb[64], cbuf[64], zb[256];
  const int n = blockIdx.x;
  const int tid = threadIdx.x;
  if (tid < 64){ hb[tid] = 0.f; cbuf[tid] = 0.f; }
  __syncthreads();
  const float bsum = bih[tid] + bhh[tid];
  for (int t = 0; t < TSTEPS; t++){
    if (tid < 32) xb[tid] = x2[(size_t)(t*NBATCH + n)*32 + tid];
    __syncthreads();
    float acc = bsum;
    #pragma unroll 8
    for (int k = 0; k < 32; k++) acc += xb[k]*wihT[k*256 + tid];
    #pragma unroll 8
    for (int k = 0; k < 64; k++) acc += hb[k]*whhT[k*256 + tid];
    zb[tid] = acc;
    __syncthreads();
    if (tid < 64){
      float zi = zb[tid], zf = zb[64 + tid], zg = zb[128 + tid], zo = zb[192 + tid];
      float c = sigf(zf)*cbuf[tid] + sigf(zi)*tanhf(zg);
      cbuf[tid] = c;
      hb[tid] = sigf(zo)*tanhf(c);
    }
    __syncthreads();
  }
  if (tid < 64){
    float v = hb[tid]*fcw[tid];
    #pragma unroll
    for (int off = 32; off > 0; off >>= 1) v += __shfl_down(v, off, 64);
    if (tid == 0) out[n] = v + fcb[0];
  }
}

extern "C" void kernel_launch(void* const* d_in, const int* in_sizes, int n_in,
                              void* d_out, int out_size, void* d_ws, size_t ws_size,
                              hipStream_t stream)
{
  const float* veg  = (const float*)d_in[0];
  const float* cwsi = (const float*)d_in[1];
  const int*   irr  = (const int*)d_in[2];
  const int*   eidx = (const int*)d_in[3];
  const float* vw1  = (const float*)d_in[4];
  const float* vg1  = (const float*)d_in[6];
  const float* vbe1 = (const float*)d_in[7];
  const float* vw2  = (const float*)d_in[8];
  const float* vg2  = (const float*)d_in[10];
  const float* vbe2 = (const float*)d_in[11];
  const float* cw1  = (const float*)d_in[12];
  const float* cg1  = (const float*)d_in[14];
  const float* cbe1 = (const float*)d_in[15];
  const float* cw2  = (const float*)d_in[16];
  const float* cg2  = (const float*)d_in[18];
  const float* cbe2 = (const float*)d_in[19];
  const float* emb  = (const float*)d_in[20];
  const float* s1wl = (const float*)d_in[21];
  const float* s1bl = (const float*)d_in[22];
  const float* s1wr = (const float*)d_in[23];
  const float* s2wl = (const float*)d_in[24];
  const float* s2bl = (const float*)d_in[25];
  const float* s2wr = (const float*)d_in[26];
  const float* wih  = (const float*)d_in[27];
  const float* whh  = (const float*)d_in[28];
  const float* bih  = (const float*)d_in[29];
  const float* bhh  = (const float*)d_in[30];
  const float* fcw  = (const float*)d_in[31];
  const float* fcb  = (const float*)d_in[32];
  float* out = (float*)d_out;

  float* ws = (float*)d_ws;
  size_t off = 0;
  float* pooled = ws + off; off += (size_t)NIMG*6400;      // 131 MB; conv1 extremum, then in-place raw z2
  float* feats  = ws + off; off += (size_t)NIMG*FEAT;
  float* agg1   = ws + off; off += (size_t)NIMG*FEAT;
  float* x1     = ws + off; off += (size_t)NIMG*64;
  float* x2     = ws + off; off += (size_t)NIMG*32;
  float* wlT    = ws + off; off += 39424;
  float* wrT    = ws + off; off += 39424;
  float* wl2T   = ws + off; off += 2048;
  float* wr2T   = ws + off; off += 2048;
  float* wihT   = ws + off; off += 8192;
  float* whhT   = ws + off; off += 16384;
  off = (off + 1) & ~(size_t)1;                            // 8B align for doubles
  double* stats = (double*)(ws + off); off += 2560;        // 1280 doubles
  float* bnp    = ws + off; off += 1280;
  int* row_start= (int*)(ws + off); off += 513;
  int* adj      = (int*)(ws + off); off += 8192;
  (void)in_sizes; (void)n_in; (void)out_size; (void)ws_size;

  prep_kernel<<<425, 256, 0, stream>>>(s1wl, s1wr, s2wl, s2wr, wih, whh,
                                       wlT, wrT, wl2T, wr2T, wihT, whhT, stats);
  csr_kernel<<<1, 512, 0, stream>>>(eidx, row_start, adj);

  double* stV1 = stats;        float* bnV1 = bnp;
  double* stV2 = stats + 320;  float* bnV2 = bnp + 320;
  double* stC1 = stats + 640;  float* bnC1 = bnp + 640;
  double* stC2 = stats + 960;  float* bnC2 = bnp + 960;

  // --- veg CNN: conv1 once (stats + signed-extremum pool), conv2 once (in-place z2), epi ---
  conv1_kernel<5><<<NIMG*3, 320, 0, stream>>>(veg, vw1, vg1, stV1, pooled);
  bn_param_kernel<<<1, 256, 0, stream>>>(stV1, bnV1, vg1, vbe1, 16, 1.0/(512.0*1600.0));
  conv2_kernel<16><<<NIMG, 256, 0, stream>>>(pooled, vw2, bnV1, stV2);
  bn_param_kernel<<<1, 256, 0, stream>>>(stV2, bnV2, vg2, vbe2, 16, 1.0/(512.0*400.0));
  conv2_epi_kernel<16><<<(NIMG*16*25 + 255)/256, 256, 0, stream>>>(pooled, bnV2, feats, 0);

  // --- cwsi CNN (reuses pooled buffer after veg epi has consumed it) ---
  conv1_kernel<1><<<NIMG*3, 320, 0, stream>>>(cwsi, cw1, cg1, stC1, pooled);
  bn_param_kernel<<<1, 256, 0, stream>>>(stC1, bnC1, cg1, cbe1, 16, 1.0/(512.0*1600.0));
  conv2_kernel<8><<<NIMG, 256, 0, stream>>>(pooled, cw2, bnC1, stC2);
  bn_param_kernel<<<1, 256, 0, stream>>>(stC2, bnC2, cg2, cbe2, 8, 1.0/(512.0*400.0));
  conv2_epi_kernel<8><<<(NIMG*8*25 + 255)/256, 256, 0, stream>>>(pooled, bnC2, feats, 400);

  // --- features tail ---
  emb_kernel<<<(NBATCH*TSTEPS*16 + 255)/256, 256, 0, stream>>>(irr, emb, feats);
  agg_kernel<<<NIMG, 256, 0, stream>>>(feats, row_start, adj, agg1);
  sage1_kernel<<<NIMG/4, 256, 0, stream>>>(feats, agg1, wlT, wrT, s1bl, x1);
  sage2_kernel<<<NIMG, 64, 0, stream>>>(x1, row_start, adj, wl2T, wr2T, s2bl, x2);
  lstm_kernel<<<NBATCH, 256, 0, stream>>>(x2, wihT, whhT, bih, bhh, fcw, fcb, out);
}

// Round 2
// 1190.358 us; speedup vs baseline: 1.3770x; 1.0484x over previous
//
#include <hip/hip_runtime.h>
#include <math.h>

#define NBATCH 512
#define TSTEPS 10
#define NIMG   5120   // NBATCH*TSTEPS
#define FEAT   616
#define NEDGE  8192

__device__ __forceinline__ float sigf(float x){ return 1.f/(1.f + expf(-x)); }

// ---------------- prep: weight transposes + zero BN stats ----------------
__global__ void prep_kernel(const float* __restrict__ s1wl, const float* __restrict__ s1wr,
                            const float* __restrict__ s2wl, const float* __restrict__ s2wr,
                            const float* __restrict__ wih,  const float* __restrict__ whh,
                            float* __restrict__ wlT, float* __restrict__ wrT,
                            float* __restrict__ wl2T, float* __restrict__ wr2T,
                            float* __restrict__ wihT, float* __restrict__ whhT,
                            double* __restrict__ stats)
{
  int idx = blockIdx.x*256 + threadIdx.x;
  if (idx < 39424){ wlT[(idx%616)*64 + idx/616] = s1wl[idx]; return; }
  idx -= 39424;
  if (idx < 39424){ wrT[(idx%616)*64 + idx/616] = s1wr[idx]; return; }
  idx -= 39424;
  if (idx < 2048){ wl2T[(idx%64)*32 + idx/64] = s2wl[idx]; return; }
  idx -= 2048;
  if (idx < 2048){ wr2T[(idx%64)*32 + idx/64] = s2wr[idx]; return; }
  idx -= 2048;
  if (idx < 8192){ wihT[(idx%32)*256 + idx/32] = wih[idx]; return; }
  idx -= 8192;
  if (idx < 16384){ whhT[(idx%64)*256 + idx/64] = whh[idx]; return; }
  idx -= 16384;
  if (idx < 1280){ stats[idx] = 0.0; }
}

// ---------------- CSR build for scatter-max (dst-grouped) ----------------
__global__ void csr_kernel(const int* __restrict__ edges, int* __restrict__ row_start,
                           int* __restrict__ adj)
{
  __shared__ int cnt_s[512];
  __shared__ int scan_s[512];
  const int tid = threadIdx.x;
  const int* src = edges;
  const int* dst = edges + NEDGE;
  cnt_s[tid] = 0;
  __syncthreads();
  for (int e = tid; e < NEDGE; e += 512) atomicAdd(&cnt_s[dst[e]], 1);
  __syncthreads();
  int v = cnt_s[tid];
  scan_s[tid] = v;
  __syncthreads();
  for (int off = 1; off < 512; off <<= 1){
    int add = (tid >= off) ? scan_s[tid - off] : 0;
    __syncthreads();
    scan_s[tid] += add;
    __syncthreads();
  }
  int start = scan_s[tid] - v;
  row_start[tid] = start;
  if (tid == 511) row_start[512] = scan_s[511];
  cnt_s[tid] = start;   // reuse as cursor
  __syncthreads();
  for (int e = tid; e < NEDGE; e += 512){
    int d = dst[e];
    int pos = atomicAdd(&cnt_s[d], 1);
    adj[pos] = src[e];
  }
}

// ---------------- conv1 (3x3 SAME, CIN->16), SINGLE PASS, FULL IMAGE ----------------
// One block per image, 320 threads. Per-thread tile: 2 rows x 10 px x 4 co.
// - zero wasted FMAs (old strip layout computed 48 rows for 40)
// - staging: structured coalesced loads (no div/mod), tiny halo-zero sweep
// - LDS row stride 46 (breaks stride-44 bank pattern; keeps 8B alignment)
// - vertical pool pair lives in-thread: no shfl, no act mask
// - stats reduced once per image (was 3x)
// BN identity (validated round 1): writes pre-BN signed extremum
// (max if g>=0 else min); conv2 applies affine+relu at stage-in. Bit-exact.
template<int CIN>
__launch_bounds__(320)
__global__ void conv1_kernel(const float* __restrict__ in, const float* __restrict__ w,
                             const float* __restrict__ g,
                             double* __restrict__ stats, float* __restrict__ pooled)
{
  constexpr int LW = 46;                 // LDS row stride (floats)
  constexpr int LIMG = 42*LW;            // per-ci LDS image size
  __shared__ __attribute__((aligned(16))) float in_t[CIN*LIMG];  // [ci][42][46]
  __shared__ __attribute__((aligned(16))) float wl[CIN*144];     // [ci][tap][16]
  __shared__ __attribute__((aligned(16))) float red[2560];       // stats scratch
  __shared__ float gsh[16];
  const int tid = threadIdx.x;
  const int img = blockIdx.x;
  const int t = img % TSTEPS;
  const float* imgp = in + (size_t)img * CIN * 1600;

  if (tid < 16) gsh[tid] = g[tid];

  // weights: [ci][tap][co]
  for (int idx = tid; idx < CIN*144; idx += 320){
    int co = idx & 15, rest = idx >> 4;
    int k = rest % 9, ci = rest / 9;
    wl[(ci*9 + k)*16 + co] = w[(co*CIN + ci)*9 + k];
  }
  // interior staging: thread (r = tid>>3, k = tid&7) loads 5 floats per ci, coalesced
  {
    const int r = tid >> 3;              // 0..39
    const int k = tid & 7;               // 0..7
    #pragma unroll
    for (int ci = 0; ci < CIN; ci++){
      const float* gp = imgp + ci*1600 + r*40 + k*5;
      float* lp = &in_t[ci*LIMG + (r + 1)*LW + 1 + k*5];
      #pragma unroll
      for (int j = 0; j < 5; j++) lp[j] = gp[j];
    }
  }
  // halo zeros: rows 0,41 (cols 0..41) + cols 0,41 (rows 1..40): 164 per ci
  for (int i = tid; i < CIN*164; i += 320){
    int ci = i / 164, rem = i % 164;
    int r, c;
    if (rem < 42){ r = 0; c = rem; }
    else if (rem < 84){ r = 41; c = rem - 42; }
    else if (rem < 124){ r = rem - 84 + 1; c = 0; }
    else { r = rem - 124 + 1; c = 41; }
    in_t[ci*LIMG + r*LW + c] = 0.f;
  }
  __syncthreads();

  // compute mapping: cog = tid/80 (4 co-groups), pos = tid%80: rp = pos>>2 (0..19), xg = pos&3
  const int cog = tid / 80, pos = tid % 80;
  const int rp = pos >> 2, xg = pos & 3;
  const int x10 = xg * 10;
  const int co0 = cog * 4;

  float acc[2][10][4];                   // [row][px][co]
  #pragma unroll
  for (int rr = 0; rr < 2; rr++)
    #pragma unroll
    for (int i = 0; i < 10; i++)
      #pragma unroll
      for (int j = 0; j < 4; j++) acc[rr][i][j] = 0.f;

  for (int ci = 0; ci < CIN; ci++){
    const float* lbase = &in_t[ci*LIMG];
    #pragma unroll
    for (int ir = 0; ir < 4; ir++){      // input rows 2rp..2rp+3 (in_t space)
      float w12[12];
      const float2* p2 = (const float2*)&lbase[(2*rp + ir)*LW + x10];
      #pragma unroll
      for (int j = 0; j < 6; j++){ float2 tv = p2[j]; w12[2*j] = tv.x; w12[2*j+1] = tv.y; }
      #pragma unroll
      for (int dy = 0; dy < 3; dy++){
        const int rr = ir - dy;
        if (rr < 0 || rr > 1) continue;  // folded at compile time
        #pragma unroll
        for (int dx = 0; dx < 3; dx++){
          const float4 wv = *(const float4*)&wl[(ci*9 + dy*3 + dx)*16 + co0];
          #pragma unroll
          for (int px = 0; px < 10; px++){
            float iv = w12[px + dx];
            acc[rr][px][0] += iv*wv.x; acc[rr][px][1] += iv*wv.y;
            acc[rr][px][2] += iv*wv.z; acc[rr][px][3] += iv*wv.w;
          }
        }
      }
    }
  }

  // ---- stats partials (pre-BN sum / sumsq over the 2x10 tile) ----
  #pragma unroll
  for (int cl = 0; cl < 4; cl++){
    float s = 0.f, q = 0.f;
    #pragma unroll
    for (int rr = 0; rr < 2; rr++)
      #pragma unroll
      for (int px = 0; px < 10; px++){
        float a = acc[rr][px][cl];
        s += a; q += a*a;
      }
    red[(co0 + cl)*80 + pos]        = s;
    red[1280 + (co0 + cl)*80 + pos] = q;
  }

  // ---- pre-BN signed extremum 2x2 pool, fully in-register ----
  #pragma unroll
  for (int cl = 0; cl < 4; cl++){
    const bool mx = gsh[co0 + cl] >= 0.f;
    float* op = &pooled[(size_t)img*6400 + (co0 + cl)*400 + rp*20 + xg*5];
    #pragma unroll
    for (int j = 0; j < 5; j++){
      float p00 = acc[0][2*j][cl], p01 = acc[0][2*j + 1][cl];
      float p10 = acc[1][2*j][cl], p11 = acc[1][2*j + 1][cl];
      float e = mx ? fmaxf(fmaxf(p00, p01), fmaxf(p10, p11))
                   : fminf(fminf(p00, p01), fminf(p10, p11));
      op[j] = e;
    }
  }
  __syncthreads();

  // ---- stats reduction (one pass per image) ----
  if (tid < 256){
    int co = tid >> 4, seg = tid & 15;
    float vs = 0.f, vq = 0.f;
    #pragma unroll
    for (int j = 0; j < 5; j++){
      vs += red[co*80 + seg*5 + j];
      vq += red[1280 + co*80 + seg*5 + j];
    }
    #pragma unroll
    for (int off = 8; off > 0; off >>= 1){
      vs += __shfl_down(vs, off, 16);
      vq += __shfl_down(vq, off, 16);
    }
    if (seg == 0){
      atomicAdd(&stats[(t*16 + co)*2 + 0], (double)vs);
      atomicAdd(&stats[(t*16 + co)*2 + 1], (double)vq);
    }
  }
}

// ---------------- conv2 (3x3 SAME, 16->CO on 20x20), SINGLE PASS ----------------
// Computes BN1 params in-block from stats (identical double math as the old
// bn_param kernel -> bit-exact), applies affine+relu at stage-in, conv once,
// accumulates conv2 stats, writes raw z2 IN-PLACE over this image's pooled
// region (all pooled reads complete before the first sync).
template<int CO>
__launch_bounds__(256)
__global__ void conv2_kernel(float* __restrict__ pooled, const float* __restrict__ w,
                             const double* __restrict__ stats1, const float* __restrict__ g1,
                             const float* __restrict__ be1, double invCnt1,
                             double* __restrict__ stats2)
{
  constexpr int R = (CO == 16) ? 2 : 1;
  constexpr int P = (20/R) * 5;                 // pixel positions: 50 or 100
  __shared__ __attribute__((aligned(16))) float in_t[16*528];   // [16][22][24] halo
  __shared__ __attribute__((aligned(16))) float wl[144*CO];     // [ci][k][CO]
  __shared__ float sc1s[16], sh1s[16];
  const int tid = threadIdx.x;
  const int img = blockIdx.x;
  const int t = img % TSTEPS;
  float* ip = pooled + (size_t)img * 6400;

  if (tid < 16){
    int c = tid;
    double mean = stats1[(t*16 + c)*2] * invCnt1;
    double var  = stats1[(t*16 + c)*2 + 1] * invCnt1 - mean*mean;
    if (var < 0.0) var = 0.0;
    double sc = (double)g1[c] / sqrt(var + 1e-5);
    sc1s[c] = (float)sc;
    sh1s[c] = be1[c] - (float)(mean * sc);
  }
  __syncthreads();

  for (int idx = tid; idx < 144*CO; idx += 256){
    int co = idx % CO, rest = idx / CO;
    int k = rest % 9, ci = rest / 9;
    wl[(ci*9 + k)*CO + co] = w[(co*16 + ci)*9 + k];
  }
  for (int idx = tid; idx < 16*528; idx += 256){
    int ci = idx / 528, rem = idx % 528;
    int r = rem / 24, cc = rem % 24;
    int gy = r - 1, gx = cc - 1;
    float v = 0.f;
    if (cc < 22 && gy >= 0 && gy < 20 && gx >= 0 && gx < 20)
      v = fmaxf(fmaf(ip[ci*400 + gy*20 + gx], sc1s[ci], sh1s[ci]), 0.f);
    in_t[idx] = v;
  }
  __syncthreads();

  const bool act = tid < P*(CO/4);
  const int q = tid % P, cog = tid / P;
  const int x4 = (q % 5) * 4, yb = (q / 5) * R;
  const int co0 = cog * 4;
  float acc[R][4][4];                           // [row][px][co]
  #pragma unroll
  for (int rr = 0; rr < R; rr++)
    #pragma unroll
    for (int i = 0; i < 4; i++)
      #pragma unroll
      for (int j = 0; j < 4; j++) acc[rr][i][j] = 0.f;

  if (act){
    for (int ci = 0; ci < 16; ci++){
      float v[R + 2][6];
      #pragma unroll
      for (int r = 0; r < R + 2; r++){
        const float* rp = &in_t[ci*528 + (yb + r)*24 + x4];
        const float4 a = *(const float4*)rp;
        const float2 b = *(const float2*)(rp + 4);
        v[r][0] = a.x; v[r][1] = a.y; v[r][2] = a.z; v[r][3] = a.w;
        v[r][4] = b.x; v[r][5] = b.y;
      }
      #pragma unroll
      for (int dy = 0; dy < 3; dy++)
        #pragma unroll
        for (int dx = 0; dx < 3; dx++){
          const float4 wv = *(const float4*)&wl[(ci*9 + dy*3 + dx)*CO + co0];
          #pragma unroll
          for (int rr = 0; rr < R; rr++){
            #pragma unroll
            for (int px = 0; px < 4; px++){
              float iv = v[rr + dy][px + dx];
              acc[rr][px][0] += iv*wv.x; acc[rr][px][1] += iv*wv.y;
              acc[rr][px][2] += iv*wv.z; acc[rr][px][3] += iv*wv.w;
            }
          }
        }
    }
  }
  __syncthreads();   // everyone done reading in_t (and ip); reuse both below

  if (act){
    #pragma unroll
    for (int cl = 0; cl < 4; cl++){
      // stats partials
      float s = 0.f, qq = 0.f;
      #pragma unroll
      for (int rr = 0; rr < R; rr++)
        #pragma unroll
        for (int px = 0; px < 4; px++){
          float a = acc[rr][px][cl];
          s += a; qq += a*a;
        }
      in_t[(co0 + cl)*P + q]            = s;
      in_t[CO*P + (co0 + cl)*P + q]     = qq;
      // raw z2 write, in place over this image's pooled region
      #pragma unroll
      for (int rr = 0; rr < R; rr++){
        float4 z4;
        z4.x = acc[rr][0][cl]; z4.y = acc[rr][1][cl];
        z4.z = acc[rr][2][cl]; z4.w = acc[rr][3][cl];
        *(float4*)&ip[(co0 + cl)*400 + (yb + rr)*20 + x4] = z4;
      }
    }
  }
  __syncthreads();
  if (tid < CO*8){
    int co = tid >> 3, seg = tid & 7;
    float vs = 0.f, vq = 0.f;
    for (int j = seg; j < P; j += 8){
      vs += in_t[co*P + j];
      vq += in_t[CO*P + co*P + j];
    }
    #pragma unroll
    for (int off = 4; off > 0; off >>= 1){
      vs += __shfl_down(vs, off, 8);
      vq += __shfl_down(vq, off, 8);
    }
    if (seg == 0){
      atomicAdd(&stats2[(t*CO + co)*2 + 0], (double)vs);
      atomicAdd(&stats2[(t*CO + co)*2 + 1], (double)vq);
    }
  }
}

// ---------------- conv2 epilogue: BN2 + relu + 4x4 avgpool -> feats ----------------
// Computes BN2 per-thread from stats (identical double math, bit-exact).
template<int CO>
__global__ void conv2_epi_kernel(const float* __restrict__ pooled, const double* __restrict__ stats2,
                                 const float* __restrict__ g2, const float* __restrict__ be2,
                                 double invCnt2, float* __restrict__ feats, int featBase)
{
  int idx = blockIdx.x*256 + threadIdx.x;
  if (idx >= NIMG*CO*25) return;
  const int q = idx % 25;
  const int rest = idx / 25;
  const int co = rest % CO, img = rest / CO;
  const int t = img % TSTEPS, n = img / TSTEPS;
  const int py = q / 5, px = q % 5;
  const float* zp = pooled + (size_t)img*6400 + co*400;
  double mean = stats2[(t*CO + co)*2] * invCnt2;
  double var  = stats2[(t*CO + co)*2 + 1] * invCnt2 - mean*mean;
  if (var < 0.0) var = 0.0;
  double scd = (double)g2[co] / sqrt(var + 1e-5);
  const float sc = (float)scd;
  const float sh = be2[co] - (float)(mean * scd);
  float s = 0.f;
  #pragma unroll
  for (int r = 0; r < 4; r++){
    const float4 v = *(const float4*)&zp[(py*4 + r)*20 + px*4];
    s += fmaxf(fmaf(v.x, sc, sh), 0.f);
    s += fmaxf(fmaf(v.y, sc, sh), 0.f);
    s += fmaxf(fmaf(v.z, sc, sh), 0.f);
    s += fmaxf(fmaf(v.w, sc, sh), 0.f);
  }
  feats[(size_t)(t*NBATCH + n)*FEAT + featBase + co*25 + q] = s * 0.0625f;
}

// ---------------- embedding fill ----------------
__global__ void emb_kernel(const int* __restrict__ irr, const float* __restrict__ emb,
                           float* __restrict__ feats)
{
  int idx = blockIdx.x*256 + threadIdx.x;
  if (idx >= NBATCH*TSTEPS*16) return;
  int k = idx & 15;
  int nt = idx >> 4;              // n*10 + t
  int t = nt % TSTEPS, n = nt / TSTEPS;
  feats[(size_t)(t*NBATCH + n)*FEAT + 600 + k] = emb[irr[nt]*16 + k];
}

// ---------------- SAGE scatter-max (CSR gather) ----------------
__global__ void agg_kernel(const float* __restrict__ feats, const int* __restrict__ row_start,
                           const int* __restrict__ adj, float* __restrict__ agg)
{
  __shared__ int adjs[192];
  const int bid = blockIdx.x;
  const int t = bid / NBATCH, n = bid % NBATCH;
  const int tid = threadIdx.x;
  const int rs = row_start[n], re = row_start[n + 1];
  const int deg = re - rs;
  for (int i = tid; i < deg && i < 192; i += 256) adjs[i] = adj[rs + i];
  __syncthreads();
  const float* fb = feats + (size_t)t*NBATCH*FEAT;
  float* ab = agg + (size_t)(t*NBATCH + n)*FEAT;
  for (int f = tid; f < FEAT; f += 256){
    float m = -1e30f;
    for (int j = 0; j < deg; j++){
      int s = (j < 192) ? adjs[j] : adj[rs + j];
      m = fmaxf(m, fb[(size_t)s*FEAT + f]);
    }
    ab[f] = (deg > 0) ? m : 0.f;
  }
}

// ---------------- SAGE1: out = relu(agg@wl^T + bl + x@wr^T), 616->64 ----------------
__launch_bounds__(256)
__global__ void sage1_kernel(const float* __restrict__ feats, const float* __restrict__ agg,
                             const float* __restrict__ wlT, const float* __restrict__ wrT,
                             const float* __restrict__ bl, float* __restrict__ x1)
{
  __shared__ float xr[4][616];
  __shared__ float ar[4][616];
  const int tid = threadIdx.x;
  const int bid = blockIdx.x;
  for (int idx = tid; idx < 4*616; idx += 256){
    int r = idx / 616, f = idx % 616;
    size_t row = (size_t)bid*4 + r;
    xr[r][f] = feats[row*FEAT + f];
    ar[r][f] = agg[row*FEAT + f];
  }
  __syncthreads();
  const int wid = tid >> 6, o = tid & 63;
  const int row = bid*4 + wid;
  float acc = bl[o];
  #pragma unroll 4
  for (int f = 0; f < 616; f++){
    acc += ar[wid][f]*wlT[f*64 + o] + xr[wid][f]*wrT[f*64 + o];
  }
  x1[(size_t)row*64 + o] = fmaxf(acc, 0.f);
}

// ---------------- SAGE2: 64->32 with its own scatter-max ----------------
__launch_bounds__(64)
__global__ void sage2_kernel(const float* __restrict__ x1, const int* __restrict__ row_start,
                             const int* __restrict__ adj, const float* __restrict__ wl2T,
                             const float* __restrict__ wr2T, const float* __restrict__ bl2,
                             float* __restrict__ x2)
{
  __shared__ float am[64], xm[64];
  __shared__ int adjs[192];
  const int bid = blockIdx.x;
  const int t = bid / NBATCH, n = bid % NBATCH;
  const int lane = threadIdx.x;
  const int rs = row_start[n], re = row_start[n + 1];
  const int deg = re - rs;
  for (int i = lane; i < deg && i < 192; i += 64) adjs[i] = adj[rs + i];
  __syncthreads();
  const float* xb = x1 + (size_t)t*NBATCH*64;
  float m = -1e30f;
  for (int j = 0; j < deg; j++){
    int s = (j < 192) ? adjs[j] : adj[rs + j];
    m = fmaxf(m, xb[s*64 + lane]);
  }
  am[lane] = (deg > 0) ? m : 0.f;
  xm[lane] = xb[n*64 + lane];
  __syncthreads();
  if (lane < 32){
    float acc = bl2[lane];
    #pragma unroll 4
    for (int f = 0; f < 64; f++){
      acc += am[f]*wl2T[f*32 + lane] + xm[f]*wr2T[f*32 + lane];
    }
    x2[(size_t)(t*NBATCH + n)*32 + lane] = fmaxf(acc, 0.f);
  }
}

// ---------------- fused LSTM (per-sample) + final FC ----------------
__launch_bounds__(256)
__global__ void lstm_kernel(const float* __restrict__ x2, const float* __restrict__ wihT,
                            const float* __restrict__ whhT, const float* __restrict__ bih,
                            const float* __restrict__ bhh, const float* __restrict__ fcw,
                            const float* __restrict__ fcb, float* __restrict__ out)
{
  __shared__ float xb[32], hb[64], cbuf[64], zb[256];
  const int n = blockIdx.x;
  const int tid = threadIdx.x;
  if (tid < 64){ hb[tid] = 0.f; cbuf[tid] = 0.f; }
  __syncthreads();
  const float bsum = bih[tid] + bhh[tid];
  for (int t = 0; t < TSTEPS; t++){
    if (tid < 32) xb[tid] = x2[(size_t)(t*NBATCH + n)*32 + tid];
    __syncthreads();
    float acc = bsum;
    #pragma unroll 8
    for (int k = 0; k < 32; k++) acc += xb[k]*wihT[k*256 + tid];
    #pragma unroll 8
    for (int k = 0; k < 64; k++) acc += hb[k]*whhT[k*256 + tid];
    zb[tid] = acc;
    __syncthreads();
    if (tid < 64){
      float zi = zb[tid], zf = zb[64 + tid], zg = zb[128 + tid], zo = zb[192 + tid];
      float c = sigf(zf)*cbuf[tid] + sigf(zi)*tanhf(zg);
      cbuf[tid] = c;
      hb[tid] = sigf(zo)*tanhf(c);
    }
    __syncthreads();
  }
  if (tid < 64){
    float v = hb[tid]*fcw[tid];
    #pragma unroll
    for (int off = 32; off > 0; off >>= 1) v += __shfl_down(v, off, 64);
    if (tid == 0) out[n] = v + fcb[0];
  }
}

extern "C" void kernel_launch(void* const* d_in, const int* in_sizes, int n_in,
                              void* d_out, int out_size, void* d_ws, size_t ws_size,
                              hipStream_t stream)
{
  const float* veg  = (const float*)d_in[0];
  const float* cwsi = (const float*)d_in[1];
  const int*   irr  = (const int*)d_in[2];
  const int*   eidx = (const int*)d_in[3];
  const float* vw1  = (const float*)d_in[4];
  const float* vg1  = (const float*)d_in[6];
  const float* vbe1 = (const float*)d_in[7];
  const float* vw2  = (const float*)d_in[8];
  const float* vg2  = (const float*)d_in[10];
  const float* vbe2 = (const float*)d_in[11];
  const float* cw1  = (const float*)d_in[12];
  const float* cg1  = (const float*)d_in[14];
  const float* cbe1 = (const float*)d_in[15];
  const float* cw2  = (const float*)d_in[16];
  const float* cg2  = (const float*)d_in[18];
  const float* cbe2 = (const float*)d_in[19];
  const float* emb  = (const float*)d_in[20];
  const float* s1wl = (const float*)d_in[21];
  const float* s1bl = (const float*)d_in[22];
  const float* s1wr = (const float*)d_in[23];
  const float* s2wl = (const float*)d_in[24];
  const float* s2bl = (const float*)d_in[25];
  const float* s2wr = (const float*)d_in[26];
  const float* wih  = (const float*)d_in[27];
  const float* whh  = (const float*)d_in[28];
  const float* bih  = (const float*)d_in[29];
  const float* bhh  = (const float*)d_in[30];
  const float* fcw  = (const float*)d_in[31];
  const float* fcb  = (const float*)d_in[32];
  float* out = (float*)d_out;

  float* ws = (float*)d_ws;
  size_t off = 0;
  float* pooled = ws + off; off += (size_t)NIMG*6400;      // 131 MB; conv1 extremum, then in-place raw z2
  float* feats  = ws + off; off += (size_t)NIMG*FEAT;
  float* agg1   = ws + off; off += (size_t)NIMG*FEAT;
  float* x1     = ws + off; off += (size_t)NIMG*64;
  float* x2     = ws + off; off += (size_t)NIMG*32;
  float* wlT    = ws + off; off += 39424;
  float* wrT    = ws + off; off += 39424;
  float* wl2T   = ws + off; off += 2048;
  float* wr2T   = ws + off; off += 2048;
  float* wihT   = ws + off; off += 8192;
  float* whhT   = ws + off; off += 16384;
  off = (off + 1) & ~(size_t)1;                            // 8B align for doubles
  double* stats = (double*)(ws + off); off += 2560;        // 1280 doubles
  int* row_start= (int*)(ws + off); off += 513;
  int* adj      = (int*)(ws + off); off += 8192;
  (void)in_sizes; (void)n_in; (void)out_size; (void)ws_size;

  prep_kernel<<<425, 256, 0, stream>>>(s1wl, s1wr, s2wl, s2wr, wih, whh,
                                       wlT, wrT, wl2T, wr2T, wihT, whhT, stats);
  csr_kernel<<<1, 512, 0, stream>>>(eidx, row_start, adj);

  double* stV1 = stats;        // conv1 veg stats
  double* stV2 = stats + 320;  // conv2 veg stats
  double* stC1 = stats + 640;  // conv1 cwsi stats
  double* stC2 = stats + 960;  // conv2 cwsi stats
  const double inv1600 = 1.0/(512.0*1600.0);
  const double inv400  = 1.0/(512.0*400.0);

  // --- veg CNN: conv1 once (stats + signed-extremum pool), conv2 once (BN1 in-block,
  //     in-place z2 + stats), epi (BN2 in-thread) ---
  conv1_kernel<5><<<NIMG, 320, 0, stream>>>(veg, vw1, vg1, stV1, pooled);
  conv2_kernel<16><<<NIMG, 256, 0, stream>>>(pooled, vw2, stV1, vg1, vbe1, inv1600, stV2);
  conv2_epi_kernel<16><<<(NIMG*16*25 + 255)/256, 256, 0, stream>>>(pooled, stV2, vg2, vbe2, inv400, feats, 0);

  // --- cwsi CNN (reuses pooled buffer after veg epi has consumed it) ---
  conv1_kernel<1><<<NIMG, 320, 0, stream>>>(cwsi, cw1, cg1, stC1, pooled);
  conv2_kernel<8><<<NIMG, 256, 0, stream>>>(pooled, cw2, stC1, cg1, cbe1, inv1600, stC2);
  conv2_epi_kernel<8><<<(NIMG*8*25 + 255)/256, 256, 0, stream>>>(pooled, stC2, cg2, cbe2, inv400, feats, 400);

  // --- features tail ---
  emb_kernel<<<(NBATCH*TSTEPS*16 + 255)/256, 256, 0, stream>>>(irr, emb, feats);
  agg_kernel<<<NIMG, 256, 0, stream>>>(feats, row_start, adj, agg1);
  sage1_kernel<<<NIMG/4, 256, 0, stream>>>(feats, agg1, wlT, wrT, s1bl, x1);
  sage2_kernel<<<NIMG, 64, 0, stream>>>(x1, row_start, adj, wl2T, wr2T, s2bl, x2);
  lstm_kernel<<<NBATCH, 256, 0, stream>>>(x2, wihT, whhT, bih, bhh, fcw, fcb, out);
}

// Round 3
// 1186.685 us; speedup vs baseline: 1.3813x; 1.0031x over previous
//
#include <hip/hip_runtime.h>
#include <math.h>

#define NBATCH 512
#define TSTEPS 10
#define NIMG   5120   // NBATCH*TSTEPS
#define FEAT   616
#define NEDGE  8192

__device__ __forceinline__ float sigf(float x){ return 1.f/(1.f + expf(-x)); }

// ---------------- prep: weight transposes + zero BN stats ----------------
__global__ void prep_kernel(const float* __restrict__ s1wl, const float* __restrict__ s1wr,
                            const float* __restrict__ s2wl, const float* __restrict__ s2wr,
                            const float* __restrict__ wih,  const float* __restrict__ whh,
                            float* __restrict__ wlT, float* __restrict__ wrT,
                            float* __restrict__ wl2T, float* __restrict__ wr2T,
                            float* __restrict__ wihT, float* __restrict__ whhT,
                            double* __restrict__ stats)
{
  int idx = blockIdx.x*256 + threadIdx.x;
  if (idx < 39424){ wlT[(idx%616)*64 + idx/616] = s1wl[idx]; return; }
  idx -= 39424;
  if (idx < 39424){ wrT[(idx%616)*64 + idx/616] = s1wr[idx]; return; }
  idx -= 39424;
  if (idx < 2048){ wl2T[(idx%64)*32 + idx/64] = s2wl[idx]; return; }
  idx -= 2048;
  if (idx < 2048){ wr2T[(idx%64)*32 + idx/64] = s2wr[idx]; return; }
  idx -= 2048;
  if (idx < 8192){ wihT[(idx%32)*256 + idx/32] = wih[idx]; return; }
  idx -= 8192;
  if (idx < 16384){ whhT[(idx%64)*256 + idx/64] = whh[idx]; return; }
  idx -= 16384;
  if (idx < 1280){ stats[idx] = 0.0; }
}

// ---------------- CSR build for scatter-max (dst-grouped) ----------------
__global__ void csr_kernel(const int* __restrict__ edges, int* __restrict__ row_start,
                           int* __restrict__ adj)
{
  __shared__ int cnt_s[512];
  __shared__ int scan_s[512];
  const int tid = threadIdx.x;
  const int* src = edges;
  const int* dst = edges + NEDGE;
  cnt_s[tid] = 0;
  __syncthreads();
  for (int e = tid; e < NEDGE; e += 512) atomicAdd(&cnt_s[dst[e]], 1);
  __syncthreads();
  int v = cnt_s[tid];
  scan_s[tid] = v;
  __syncthreads();
  for (int off = 1; off < 512; off <<= 1){
    int add = (tid >= off) ? scan_s[tid - off] : 0;
    __syncthreads();
    scan_s[tid] += add;
    __syncthreads();
  }
  int start = scan_s[tid] - v;
  row_start[tid] = start;
  if (tid == 511) row_start[512] = scan_s[511];
  cnt_s[tid] = start;   // reuse as cursor
  __syncthreads();
  for (int e = tid; e < NEDGE; e += 512){
    int d = dst[e];
    int pos = atomicAdd(&cnt_s[d], 1);
    adj[pos] = src[e];
  }
}

// ---------------- conv1 (3x3 SAME, CIN->16), SINGLE PASS, 2 STRIPS ----------------
// Grid NIMG*2 blocks, 320 threads; strip = 20 output rows (exact cover, no
// wasted FMAs, no act masks: 8 co-groups x 40 pos = 320 = 16co x 20row x 40px
// with per-thread tile 2 rows x 10 px x 2 co).
// LDS: in_t CIN*22*46 (reused as stats scratch after sync) + weights.
// ~23KB @ CIN=5 -> ~6 blocks/CU (vs 52KB/low-occupancy full-image version).
// BN identity (validated round 1): writes pre-BN signed extremum (max if
// g>=0 else min); conv2 applies affine+relu at stage-in. Bit-exact.
template<int CIN>
__launch_bounds__(320)
__global__ void conv1_kernel(const float* __restrict__ in, const float* __restrict__ w,
                             const float* __restrict__ g,
                             double* __restrict__ stats, float* __restrict__ pooled)
{
  constexpr int LW = 46;                   // LDS row stride (floats)
  constexpr int LIMG = 22*LW;              // per-ci LDS strip size (1012)
  constexpr int INTSZ = (CIN*LIMG > 1280) ? CIN*LIMG : 1280;  // stats scratch fits
  __shared__ __attribute__((aligned(16))) float in_t[INTSZ];
  __shared__ __attribute__((aligned(16))) float wl[CIN*144];  // [ci][tap][16]
  __shared__ float gsh[16];
  const int tid = threadIdx.x;
  const int bid = blockIdx.x;
  const int img = bid >> 1, strip = bid & 1;
  const int y0 = strip * 20;
  const int t = img % TSTEPS;
  const float* imgp = in + (size_t)img * CIN * 1600;

  if (tid < 16) gsh[tid] = g[tid];

  // weights: [ci][tap][co]
  for (int idx = tid; idx < CIN*144; idx += 320){
    int co = idx & 15, rest = idx >> 4;
    int k = rest % 9, ci = rest / 9;
    wl[(ci*9 + k)*16 + co] = w[(co*CIN + ci)*9 + k];
  }
  // interior staging, coalesced 40-lane rows
  {
    const int c = tid % 40, rg = tid / 40;          // rg 0..7
    #pragma unroll
    for (int ci = 0; ci < CIN; ci++){
      #pragma unroll
      for (int j = 0; j < 3; j++){
        int r = rg + 8*j;                           // 0..21
        if (r < 22){
          int gy = y0 + r - 1;
          in_t[ci*LIMG + r*LW + c + 1] =
              (gy >= 0 && gy < 40) ? imgp[ci*1600 + gy*40 + c] : 0.f;
        }
      }
    }
  }
  // halo cols 0 and 41
  for (int i = tid; i < CIN*22; i += 320){
    int ci = i / 22, r = i % 22;
    in_t[ci*LIMG + r*LW + 0]  = 0.f;
    in_t[ci*LIMG + r*LW + 41] = 0.f;
  }
  __syncthreads();

  // mapping: cog = tid/40 (8 groups of 2 co), pos = tid%40: rp 0..9, xg 0..3
  const int cog = tid / 40, pos = tid % 40;
  const int rp = pos >> 2, xg = pos & 3;
  const int x10 = xg * 10;
  const int co0 = cog * 2;

  float acc[2][10][2];                     // [row][px][co]
  #pragma unroll
  for (int rr = 0; rr < 2; rr++)
    #pragma unroll
    for (int i = 0; i < 10; i++)
      #pragma unroll
      for (int j = 0; j < 2; j++) acc[rr][i][j] = 0.f;

  for (int ci = 0; ci < CIN; ci++){
    const float* lbase = &in_t[ci*LIMG];
    #pragma unroll
    for (int ir = 0; ir < 4; ir++){        // in_t rows 2rp..2rp+3
      float w12[12];
      const float2* p2 = (const float2*)&lbase[(2*rp + ir)*LW + x10];
      #pragma unroll
      for (int j = 0; j < 6; j++){ float2 tv = p2[j]; w12[2*j] = tv.x; w12[2*j+1] = tv.y; }
      #pragma unroll
      for (int dy = 0; dy < 3; dy++){
        const int rr = ir - dy;
        if (rr < 0 || rr > 1) continue;    // folded at compile time
        #pragma unroll
        for (int dx = 0; dx < 3; dx++){
          const float2 wv = *(const float2*)&wl[(ci*9 + dy*3 + dx)*16 + co0];
          #pragma unroll
          for (int px = 0; px < 10; px++){
            float iv = w12[px + dx];
            acc[rr][px][0] += iv*wv.x; acc[rr][px][1] += iv*wv.y;
          }
        }
      }
    }
  }
  __syncthreads();   // all in_t reads done; reuse as stats scratch

  // ---- stats partials into reused in_t: [16][40] sums, [16][40] sumsqs ----
  #pragma unroll
  for (int cl = 0; cl < 2; cl++){
    float s = 0.f, q = 0.f;
    #pragma unroll
    for (int rr = 0; rr < 2; rr++)
      #pragma unroll
      for (int px = 0; px < 10; px++){
        float a = acc[rr][px][cl];
        s += a; q += a*a;
      }
    in_t[(co0 + cl)*40 + pos]       = s;
    in_t[640 + (co0 + cl)*40 + pos] = q;
  }

  // ---- pre-BN signed extremum 2x2 pool, fully in-register ----
  const int py = strip*10 + rp;
  #pragma unroll
  for (int cl = 0; cl < 2; cl++){
    const bool mx = gsh[co0 + cl] >= 0.f;
    float* op = &pooled[(size_t)img*6400 + (co0 + cl)*400 + py*20 + xg*5];
    #pragma unroll
    for (int j = 0; j < 5; j++){
      float p00 = acc[0][2*j][cl], p01 = acc[0][2*j + 1][cl];
      float p10 = acc[1][2*j][cl], p11 = acc[1][2*j + 1][cl];
      float e = mx ? fmaxf(fmaxf(p00, p01), fmaxf(p10, p11))
                   : fminf(fminf(p00, p01), fminf(p10, p11));
      op[j] = e;
    }
  }
  __syncthreads();

  // ---- stats reduction ----
  if (tid < 128){
    int co = tid >> 3, seg = tid & 7;
    float vs = 0.f, vq = 0.f;
    #pragma unroll
    for (int j = 0; j < 5; j++){
      vs += in_t[co*40 + seg*5 + j];
      vq += in_t[640 + co*40 + seg*5 + j];
    }
    #pragma unroll
    for (int off = 4; off > 0; off >>= 1){
      vs += __shfl_down(vs, off, 8);
      vq += __shfl_down(vq, off, 8);
    }
    if (seg == 0){
      atomicAdd(&stats[(t*16 + co)*2 + 0], (double)vs);
      atomicAdd(&stats[(t*16 + co)*2 + 1], (double)vq);
    }
  }
}

// ---------------- conv2 (3x3 SAME, 16->CO on 20x20), SINGLE PASS ----------------
// Computes BN1 params in-block from stats (identical double math, bit-exact),
// applies affine+relu at stage-in, conv once, accumulates conv2 stats, writes
// raw z2 IN-PLACE over this image's pooled region.
template<int CO>
__launch_bounds__(256)
__global__ void conv2_kernel(float* __restrict__ pooled, const float* __restrict__ w,
                             const double* __restrict__ stats1, const float* __restrict__ g1,
                             const float* __restrict__ be1, double invCnt1,
                             double* __restrict__ stats2)
{
  constexpr int R = (CO == 16) ? 2 : 1;
  constexpr int P = (20/R) * 5;                 // pixel positions: 50 or 100
  __shared__ __attribute__((aligned(16))) float in_t[16*528];   // [16][22][24] halo
  __shared__ __attribute__((aligned(16))) float wl[144*CO];     // [ci][k][CO]
  __shared__ float sc1s[16], sh1s[16];
  const int tid = threadIdx.x;
  const int img = blockIdx.x;
  const int t = img % TSTEPS;
  float* ip = pooled + (size_t)img * 6400;

  if (tid < 16){
    int c = tid;
    double mean = stats1[(t*16 + c)*2] * invCnt1;
    double var  = stats1[(t*16 + c)*2 + 1] * invCnt1 - mean*mean;
    if (var < 0.0) var = 0.0;
    double sc = (double)g1[c] / sqrt(var + 1e-5);
    sc1s[c] = (float)sc;
    sh1s[c] = be1[c] - (float)(mean * sc);
  }
  __syncthreads();

  for (int idx = tid; idx < 144*CO; idx += 256){
    int co = idx % CO, rest = idx / CO;
    int k = rest % 9, ci = rest / 9;
    wl[(ci*9 + k)*CO + co] = w[(co*16 + ci)*9 + k];
  }
  for (int idx = tid; idx < 16*528; idx += 256){
    int ci = idx / 528, rem = idx % 528;
    int r = rem / 24, cc = rem % 24;
    int gy = r - 1, gx = cc - 1;
    float v = 0.f;
    if (cc < 22 && gy >= 0 && gy < 20 && gx >= 0 && gx < 20)
      v = fmaxf(fmaf(ip[ci*400 + gy*20 + gx], sc1s[ci], sh1s[ci]), 0.f);
    in_t[idx] = v;
  }
  __syncthreads();

  const bool act = tid < P*(CO/4);
  const int q = tid % P, cog = tid / P;
  const int x4 = (q % 5) * 4, yb = (q / 5) * R;
  const int co0 = cog * 4;
  float acc[R][4][4];                           // [row][px][co]
  #pragma unroll
  for (int rr = 0; rr < R; rr++)
    #pragma unroll
    for (int i = 0; i < 4; i++)
      #pragma unroll
      for (int j = 0; j < 4; j++) acc[rr][i][j] = 0.f;

  if (act){
    for (int ci = 0; ci < 16; ci++){
      float v[R + 2][6];
      #pragma unroll
      for (int r = 0; r < R + 2; r++){
        const float* rp = &in_t[ci*528 + (yb + r)*24 + x4];
        const float4 a = *(const float4*)rp;
        const float2 b = *(const float2*)(rp + 4);
        v[r][0] = a.x; v[r][1] = a.y; v[r][2] = a.z; v[r][3] = a.w;
        v[r][4] = b.x; v[r][5] = b.y;
      }
      #pragma unroll
      for (int dy = 0; dy < 3; dy++)
        #pragma unroll
        for (int dx = 0; dx < 3; dx++){
          const float4 wv = *(const float4*)&wl[(ci*9 + dy*3 + dx)*CO + co0];
          #pragma unroll
          for (int rr = 0; rr < R; rr++){
            #pragma unroll
            for (int px = 0; px < 4; px++){
              float iv = v[rr + dy][px + dx];
              acc[rr][px][0] += iv*wv.x; acc[rr][px][1] += iv*wv.y;
              acc[rr][px][2] += iv*wv.z; acc[rr][px][3] += iv*wv.w;
            }
          }
        }
    }
  }
  __syncthreads();   // everyone done reading in_t (and ip); reuse both below

  if (act){
    #pragma unroll
    for (int cl = 0; cl < 4; cl++){
      // stats partials
      float s = 0.f, qq = 0.f;
      #pragma unroll
      for (int rr = 0; rr < R; rr++)
        #pragma unroll
        for (int px = 0; px < 4; px++){
          float a = acc[rr][px][cl];
          s += a; qq += a*a;
        }
      in_t[(co0 + cl)*P + q]            = s;
      in_t[CO*P + (co0 + cl)*P + q]     = qq;
      // raw z2 write, in place over this image's pooled region
      #pragma unroll
      for (int rr = 0; rr < R; rr++){
        float4 z4;
        z4.x = acc[rr][0][cl]; z4.y = acc[rr][1][cl];
        z4.z = acc[rr][2][cl]; z4.w = acc[rr][3][cl];
        *(float4*)&ip[(co0 + cl)*400 + (yb + rr)*20 + x4] = z4;
      }
    }
  }
  __syncthreads();
  if (tid < CO*8){
    int co = tid >> 3, seg = tid & 7;
    float vs = 0.f, vq = 0.f;
    for (int j = seg; j < P; j += 8){
      vs += in_t[co*P + j];
      vq += in_t[CO*P + co*P + j];
    }
    #pragma unroll
    for (int off = 4; off > 0; off >>= 1){
      vs += __shfl_down(vs, off, 8);
      vq += __shfl_down(vq, off, 8);
    }
    if (seg == 0){
      atomicAdd(&stats2[(t*CO + co)*2 + 0], (double)vs);
      atomicAdd(&stats2[(t*CO + co)*2 + 1], (double)vq);
    }
  }
}

// ---------------- conv2 epilogue: BN2 + relu + 4x4 avgpool -> feats ----------------
template<int CO>
__global__ void conv2_epi_kernel(const float* __restrict__ pooled, const double* __restrict__ stats2,
                                 const float* __restrict__ g2, const float* __restrict__ be2,
                                 double invCnt2, float* __restrict__ feats, int featBase)
{
  int idx = blockIdx.x*256 + threadIdx.x;
  if (idx >= NIMG*CO*25) return;
  const int q = idx % 25;
  const int rest = idx / 25;
  const int co = rest % CO, img = rest / CO;
  const int t = img % TSTEPS, n = img / TSTEPS;
  const int py = q / 5, px = q % 5;
  const float* zp = pooled + (size_t)img*6400 + co*400;
  double mean = stats2[(t*CO + co)*2] * invCnt2;
  double var  = stats2[(t*CO + co)*2 + 1] * invCnt2 - mean*mean;
  if (var < 0.0) var = 0.0;
  double scd = (double)g2[co] / sqrt(var + 1e-5);
  const float sc = (float)scd;
  const float sh = be2[co] - (float)(mean * scd);
  float s = 0.f;
  #pragma unroll
  for (int r = 0; r < 4; r++){
    const float4 v = *(const float4*)&zp[(py*4 + r)*20 + px*4];
    s += fmaxf(fmaf(v.x, sc, sh), 0.f);
    s += fmaxf(fmaf(v.y, sc, sh), 0.f);
    s += fmaxf(fmaf(v.z, sc, sh), 0.f);
    s += fmaxf(fmaf(v.w, sc, sh), 0.f);
  }
  feats[(size_t)(t*NBATCH + n)*FEAT + featBase + co*25 + q] = s * 0.0625f;
}

// ---------------- embedding fill ----------------
__global__ void emb_kernel(const int* __restrict__ irr, const float* __restrict__ emb,
                           float* __restrict__ feats)
{
  int idx = blockIdx.x*256 + threadIdx.x;
  if (idx >= NBATCH*TSTEPS*16) return;
  int k = idx & 15;
  int nt = idx >> 4;              // n*10 + t
  int t = nt % TSTEPS, n = nt / TSTEPS;
  feats[(size_t)(t*NBATCH + n)*FEAT + 600 + k] = emb[irr[nt]*16 + k];
}

// ---------------- SAGE1 with FUSED scatter-max gather ----------------
// Each block: 4 rows (same t). Gathers agg = scatter-max(feats) for its rows
// directly (same ascending-j fmax order as before -> bit-exact), then
// out = relu(agg@wl^T + bl + x@wr^T). Eliminates the agg buffer round-trip.
__launch_bounds__(256)
__global__ void sage1_kernel(const float* __restrict__ feats, const int* __restrict__ row_start,
                             const int* __restrict__ adj,
                             const float* __restrict__ wlT, const float* __restrict__ wrT,
                             const float* __restrict__ bl, float* __restrict__ x1)
{
  __shared__ float xr[4][616];
  __shared__ float ar[4][616];
  __shared__ int adjs[4][192];
  const int tid = threadIdx.x;
  const int bid = blockIdx.x;
  const int row0 = bid*4;
  const int t = row0 / NBATCH, n0 = row0 % NBATCH;
  const float* fb = feats + (size_t)t*NBATCH*FEAT;

  // stage x rows
  for (int idx = tid; idx < 4*616; idx += 256){
    int r = idx / 616, f = idx % 616;
    xr[r][f] = fb[(size_t)(n0 + r)*FEAT + f];
  }
  // stage adjacency for the 4 rows
  #pragma unroll
  for (int r = 0; r < 4; r++){
    int rs = row_start[n0 + r], re = row_start[n0 + r + 1];
    int deg = re - rs;
    for (int i = tid; i < deg && i < 192; i += 256) adjs[r][i] = adj[rs + i];
  }
  __syncthreads();

  // gather-max into ar (ascending j, identical order to old agg_kernel)
  #pragma unroll
  for (int r = 0; r < 4; r++){
    const int rs = row_start[n0 + r], re = row_start[n0 + r + 1];
    const int deg = re - rs;
    for (int f = tid; f < 616; f += 256){
      float m = -1e30f;
      for (int j = 0; j < deg; j++){
        int s = (j < 192) ? adjs[r][j] : adj[rs + j];
        m = fmaxf(m, fb[(size_t)s*FEAT + f]);
      }
      ar[r][f] = (deg > 0) ? m : 0.f;
    }
  }
  __syncthreads();

  const int wid = tid >> 6, o = tid & 63;
  const int row = row0 + wid;
  float acc = bl[o];
  #pragma unroll 4
  for (int f = 0; f < 616; f++){
    acc += ar[wid][f]*wlT[f*64 + o] + xr[wid][f]*wrT[f*64 + o];
  }
  x1[(size_t)row*64 + o] = fmaxf(acc, 0.f);
}

// ---------------- SAGE2: 64->32 with its own scatter-max ----------------
__launch_bounds__(64)
__global__ void sage2_kernel(const float* __restrict__ x1, const int* __restrict__ row_start,
                             const int* __restrict__ adj, const float* __restrict__ wl2T,
                             const float* __restrict__ wr2T, const float* __restrict__ bl2,
                             float* __restrict__ x2)
{
  __shared__ float am[64], xm[64];
  __shared__ int adjs[192];
  const int bid = blockIdx.x;
  const int t = bid / NBATCH, n = bid % NBATCH;
  const int lane = threadIdx.x;
  const int rs = row_start[n], re = row_start[n + 1];
  const int deg = re - rs;
  for (int i = lane; i < deg && i < 192; i += 64) adjs[i] = adj[rs + i];
  __syncthreads();
  const float* xb = x1 + (size_t)t*NBATCH*64;
  float m = -1e30f;
  for (int j = 0; j < deg; j++){
    int s = (j < 192) ? adjs[j] : adj[rs + j];
    m = fmaxf(m, xb[s*64 + lane]);
  }
  am[lane] = (deg > 0) ? m : 0.f;
  xm[lane] = xb[n*64 + lane];
  __syncthreads();
  if (lane < 32){
    float acc = bl2[lane];
    #pragma unroll 4
    for (int f = 0; f < 64; f++){
      acc += am[f]*wl2T[f*32 + lane] + xm[f]*wr2T[f*32 + lane];
    }
    x2[(size_t)(t*NBATCH + n)*32 + lane] = fmaxf(acc, 0.f);
  }
}

// ---------------- fused LSTM (per-sample) + final FC ----------------
__launch_bounds__(256)
__global__ void lstm_kernel(const float* __restrict__ x2, const float* __restrict__ wihT,
                            const float* __restrict__ whhT, const float* __restrict__ bih,
                            const float* __restrict__ bhh, const float* __restrict__ fcw,
                            const float* __restrict__ fcb, float* __restrict__ out)
{
  __shared__ float xb[32], hb[64], cbuf[64], zb[256];
  const int n = blockIdx.x;
  const int tid = threadIdx.x;
  if (tid < 64){ hb[tid] = 0.f; cbuf[tid] = 0.f; }
  __syncthreads();
  const float bsum = bih[tid] + bhh[tid];
  for (int t = 0; t < TSTEPS; t++){
    if (tid < 32) xb[tid] = x2[(size_t)(t*NBATCH + n)*32 + tid];
    __syncthreads();
    float acc = bsum;
    #pragma unroll 8
    for (int k = 0; k < 32; k++) acc += xb[k]*wihT[k*256 + tid];
    #pragma unroll 8
    for (int k = 0; k < 64; k++) acc += hb[k]*whhT[k*256 + tid];
    zb[tid] = acc;
    __syncthreads();
    if (tid < 64){
      float zi = zb[tid], zf = zb[64 + tid], zg = zb[128 + tid], zo = zb[192 + tid];
      float c = sigf(zf)*cbuf[tid] + sigf(zi)*tanhf(zg);
      cbuf[tid] = c;
      hb[tid] = sigf(zo)*tanhf(c);
    }
    __syncthreads();
  }
  if (tid < 64){
    float v = hb[tid]*fcw[tid];
    #pragma unroll
    for (int off = 32; off > 0; off >>= 1) v += __shfl_down(v, off, 64);
    if (tid == 0) out[n] = v + fcb[0];
  }
}

extern "C" void kernel_launch(void* const* d_in, const int* in_sizes, int n_in,
                              void* d_out, int out_size, void* d_ws, size_t ws_size,
                              hipStream_t stream)
{
  const float* veg  = (const float*)d_in[0];
  const float* cwsi = (const float*)d_in[1];
  const int*   irr  = (const int*)d_in[2];
  const int*   eidx = (const int*)d_in[3];
  const float* vw1  = (const float*)d_in[4];
  const float* vg1  = (const float*)d_in[6];
  const float* vbe1 = (const float*)d_in[7];
  const float* vw2  = (const float*)d_in[8];
  const float* vg2  = (const float*)d_in[10];
  const float* vbe2 = (const float*)d_in[11];
  const float* cw1  = (const float*)d_in[12];
  const float* cg1  = (const float*)d_in[14];
  const float* cbe1 = (const float*)d_in[15];
  const float* cw2  = (const float*)d_in[16];
  const float* cg2  = (const float*)d_in[18];
  const float* cbe2 = (const float*)d_in[19];
  const float* emb  = (const float*)d_in[20];
  const float* s1wl = (const float*)d_in[21];
  const float* s1bl = (const float*)d_in[22];
  const float* s1wr = (const float*)d_in[23];
  const float* s2wl = (const float*)d_in[24];
  const float* s2bl = (const float*)d_in[25];
  const float* s2wr = (const float*)d_in[26];
  const float* wih  = (const float*)d_in[27];
  const float* whh  = (const float*)d_in[28];
  const float* bih  = (const float*)d_in[29];
  const float* bhh  = (const float*)d_in[30];
  const float* fcw  = (const float*)d_in[31];
  const float* fcb  = (const float*)d_in[32];
  float* out = (float*)d_out;

  float* ws = (float*)d_ws;
  size_t off = 0;
  float* pooled = ws + off; off += (size_t)NIMG*6400;      // 131 MB; conv1 extremum, then in-place raw z2
  float* feats  = ws + off; off += (size_t)NIMG*FEAT;
  float* x1     = ws + off; off += (size_t)NIMG*64;
  float* x2     = ws + off; off += (size_t)NIMG*32;
  float* wlT    = ws + off; off += 39424;
  float* wrT    = ws + off; off += 39424;
  float* wl2T   = ws + off; off += 2048;
  float* wr2T   = ws + off; off += 2048;
  float* wihT   = ws + off; off += 8192;
  float* whhT   = ws + off; off += 16384;
  off = (off + 1) & ~(size_t)1;                            // 8B align for doubles
  double* stats = (double*)(ws + off); off += 2560;        // 1280 doubles
  int* row_start= (int*)(ws + off); off += 513;
  int* adj      = (int*)(ws + off); off += 8192;
  (void)in_sizes; (void)n_in; (void)out_size; (void)ws_size;

  prep_kernel<<<425, 256, 0, stream>>>(s1wl, s1wr, s2wl, s2wr, wih, whh,
                                       wlT, wrT, wl2T, wr2T, wihT, whhT, stats);
  csr_kernel<<<1, 512, 0, stream>>>(eidx, row_start, adj);

  double* stV1 = stats;        // conv1 veg stats
  double* stV2 = stats + 320;  // conv2 veg stats
  double* stC1 = stats + 640;  // conv1 cwsi stats
  double* stC2 = stats + 960;  // conv2 cwsi stats
  const double inv1600 = 1.0/(512.0*1600.0);
  const double inv400  = 1.0/(512.0*400.0);

  // --- veg CNN ---
  conv1_kernel<5><<<NIMG*2, 320, 0, stream>>>(veg, vw1, vg1, stV1, pooled);
  conv2_kernel<16><<<NIMG, 256, 0, stream>>>(pooled, vw2, stV1, vg1, vbe1, inv1600, stV2);
  conv2_epi_kernel<16><<<(NIMG*16*25 + 255)/256, 256, 0, stream>>>(pooled, stV2, vg2, vbe2, inv400, feats, 0);

  // --- cwsi CNN (reuses pooled buffer after veg epi has consumed it) ---
  conv1_kernel<1><<<NIMG*2, 320, 0, stream>>>(cwsi, cw1, cg1, stC1, pooled);
  conv2_kernel<8><<<NIMG, 256, 0, stream>>>(pooled, cw2, stC1, cg1, cbe1, inv1600, stC2);
  conv2_epi_kernel<8><<<(NIMG*8*25 + 255)/256, 256, 0, stream>>>(pooled, stC2, cg2, cbe2, inv400, feats, 400);

  // --- features tail ---
  emb_kernel<<<(NBATCH*TSTEPS*16 + 255)/256, 256, 0, stream>>>(irr, emb, feats);
  sage1_kernel<<<NIMG/4, 256, 0, stream>>>(feats, row_start, adj, wlT, wrT, s1bl, x1);
  sage2_kernel<<<NIMG, 64, 0, stream>>>(x1, row_start, adj, wl2T, wr2T, s2bl, x2);
  lstm_kernel<<<NBATCH, 256, 0, stream>>>(x2, wihT, whhT, bih, bhh, fcw, fcb, out);
}